// Round 1
// baseline (2857.776 us; speedup 1.0000x reference)
//
#include <hip/hip_runtime.h>

#define DEV __device__ __forceinline__

typedef unsigned short u16;
using bf16x8 = __attribute__((ext_vector_type(8))) __bf16;
using f32x4  = __attribute__((ext_vector_type(4))) float;

DEV u16 f2bf(float f){
  unsigned u = __float_as_uint(f);
  u += 0x7fffu + ((u >> 16) & 1u);   // round-to-nearest-even
  return (u16)(u >> 16);
}
DEV float sigf(float x){ return 1.f / (1.f + __expf(-x)); }
DEV float tanh_(float x){ return 2.f / (1.f + __expf(-2.f*x)) - 1.f; } // safe at +/-inf

DEV void async16(const u16* g, u16* l){
  __builtin_amdgcn_global_load_lds(
      (const __attribute__((address_space(1))) unsigned int*)g,
      (__attribute__((address_space(3))) unsigned int*)l, 16, 0, 0);
}

// ---------------- BatchNorm (training-mode batch stats, biased var) ----------
__global__ void bn_stats(const float* __restrict__ z, float* __restrict__ ps, float* __restrict__ pq){
  int bx = blockIdx.x; int rg = bx >> 2, cg = bx & 3;
  int c = cg*256 + threadIdx.x;
  float s = 0.f, q = 0.f;
  for (int r = rg*64; r < rg*64 + 64; ++r){ float v = z[r*1024 + c]; s += v; q += v*v; }
  ps[rg*1024 + c] = s; pq[rg*1024 + c] = q;
}

__global__ void bn_fin(const float* __restrict__ ps, const float* __restrict__ pq,
                       const float* __restrict__ gam, const float* __restrict__ bet,
                       float* __restrict__ sc, float* __restrict__ sh){
  int c = blockIdx.x*256 + threadIdx.x;
  float s = 0.f, q = 0.f;
  for (int rg = 0; rg < 16; ++rg){ s += ps[rg*1024 + c]; q += pq[rg*1024 + c]; }
  float mean = s * (1.f/1024.f);
  float var  = q * (1.f/1024.f) - mean*mean;
  float k = gam[c] * rsqrtf(var + 1e-5f);
  sc[c] = k; sh[c] = bet[c] - mean*k;
}

// zn -> h0 (bf16), h1 (bf16), c0 (f32), c1 (f32)
__global__ void bn_norm(const float* __restrict__ z, const float* __restrict__ sc, const float* __restrict__ sh,
                        u16* __restrict__ h0, u16* __restrict__ h1,
                        float* __restrict__ c0, float* __restrict__ c1){
  int bx = blockIdx.x; int rg = bx >> 2, cg = bx & 3;
  int c = cg*256 + threadIdx.x;
  float k = sc[c], b = sh[c];
  for (int r = rg*64; r < rg*64 + 64; ++r){
    float v = z[r*1024 + c]*k + b;
    u16 hv = f2bf(v);
    h0[r*1024 + c] = hv; h1[r*1024 + c] = hv;
    c0[r*1024 + c] = v;  c1[r*1024 + c] = v;
  }
}

// ---------------- weight convert (+gate-interleave permutation) --------------
// permuted col c: gate=(c>>4)&3, unit u=(c&15)|((c>>6)<<4) -> src row gate*1024+u
__global__ void conv_w(const float* __restrict__ src, u16* __restrict__ dst,
                       int dstStride, int colOff, int permute){
  int c = blockIdx.x;
  int row = c;
  if (permute){ int gate = (c>>4)&3; int u = (c&15) | ((c>>6)<<4); row = (gate<<10) + u; }
  float4 v = ((const float4*)(src + (size_t)row*1024))[threadIdx.x];
  ushort4 o; o.x = f2bf(v.x); o.y = f2bf(v.y); o.z = f2bf(v.z); o.w = f2bf(v.w);
  ((ushort4*)(dst + (size_t)c*dstStride + colOff))[threadIdx.x] = o;
}

__global__ void bias_k(const float* __restrict__ bi0, const float* __restrict__ bh0,
                       const float* __restrict__ bi1, const float* __restrict__ bh1,
                       float* __restrict__ bx0, float* __restrict__ b1){
  int c = blockIdx.x*256 + threadIdx.x;           // 0..4095
  int gate = (c>>4)&3; int u = (c&15) | ((c>>6)<<4); int r = (gate<<10) + u;
  bx0[c] = bi0[r] + bh0[r];
  b1[c]  = bi1[r] + bh1[r];
}

// ---------------- GEMM: C(128x128) = A(M,K) @ B(N,K)^T, bf16 MFMA ------------
// MODE 0: store f32 gates+bias (x0 projection) to outf (ld 4096)
// MODE 1: LSTM layer-0 epilogue (add = x0proj matrix, incl. both biases)
// MODE 2: LSTM layer-1 epilogue (add = bias per col); also writes feats
// MODE 3: store f32 out + bias (ld 1024), unpermuted (linear head)
template<int MODE>
__global__ __launch_bounds__(256)
void gemm_k(const u16* __restrict__ A0, const u16* __restrict__ A1, int KloA,
            const u16* __restrict__ Bm, int K,
            const float* __restrict__ add,
            float* __restrict__ cst,
            u16* __restrict__ hout, u16* __restrict__ hout2,
            float* __restrict__ outf)
{
  __shared__ u16 sA[128*32];
  __shared__ u16 sB[128*32];
  const int t = threadIdx.x;
  const int lane = t & 63;
  const int w = t >> 6, wm = w >> 1, wn = w & 1;
  const int bx = blockIdx.x, by = blockIdx.y;
  const int m0 = by*128, n0 = bx*128;

  f32x4 acc[4][4];
#pragma unroll
  for (int i = 0; i < 4; ++i)
#pragma unroll
    for (int j = 0; j < 4; ++j) acc[i][j] = (f32x4){0.f,0.f,0.f,0.f};

  const int rA = t >> 2;            // staging chunk row (q=0); q=1 adds 64
  const int kp = (t & 3) * 8;       // k-offset within 32-wide tile
  const int nkt = K >> 5;

  for (int kt = 0; kt < nkt; ++kt){
    const int k0 = kt << 5;
    const u16* aPart; int kk;
    if (k0 < KloA){ aPart = A0; kk = k0; } else { aPart = A1; kk = k0 - KloA; }
#pragma unroll
    for (int q = 0; q < 2; ++q){
      int row = rA + q*64;
      async16(aPart + (size_t)(m0 + row)*1024 + kk + kp, &sA[(t + q*256)*8]);
      async16(Bm    + (size_t)(n0 + row)*K    + k0 + kp, &sB[(t + q*256)*8]);
    }
    __syncthreads();                 // vmcnt(0) drain + barrier: tiles ready
    bf16x8 af[4], bfr[4];
#pragma unroll
    for (int i = 0; i < 4; ++i){
      af[i]  = *(const bf16x8*)&sA[(wm*64 + i*16 + (lane & 15))*32 + (lane >> 4)*8];
      bfr[i] = *(const bf16x8*)&sB[(wn*64 + i*16 + (lane & 15))*32 + (lane >> 4)*8];
    }
#pragma unroll
    for (int i = 0; i < 4; ++i)
#pragma unroll
      for (int j = 0; j < 4; ++j)
        acc[i][j] = __builtin_amdgcn_mfma_f32_16x16x32_bf16(af[i], bfr[j], acc[i][j], 0, 0, 0);
    __syncthreads();                 // protect LDS before next staging
  }

  const int s  = lane & 15;
  const int rq = (lane >> 4) * 4;

  if constexpr (MODE == 0 || MODE == 3){
    const int ldc = (MODE == 0) ? 4096 : 1024;
#pragma unroll
    for (int j = 0; j < 4; ++j){
      int col = n0 + wn*64 + j*16 + s;
      float bj = add[col];
#pragma unroll
      for (int i = 0; i < 4; ++i){
        int rowb = m0 + wm*64 + i*16 + rq;
#pragma unroll
        for (int r = 0; r < 4; ++r)
          outf[(size_t)(rowb + r)*ldc + col] = acc[i][j][r] + bj;
      }
    }
  } else {
    const int u = s + ((bx*2 + wn) << 4);     // hidden-unit index 0..1023
    int cidx[4]; float bj[4];
#pragma unroll
    for (int j = 0; j < 4; ++j){
      cidx[j] = n0 + wn*64 + j*16 + s;        // gate j lives at this col
      if (MODE == 2) bj[j] = add[cidx[j]];
    }
#pragma unroll
    for (int i = 0; i < 4; ++i){
      int rowb = m0 + wm*64 + i*16 + rq;
#pragma unroll
      for (int r = 0; r < 4; ++r){
        int row = rowb + r;
        float g0, g1, g2, g3;
        if (MODE == 1){
          const float* xp = add + (size_t)row*4096;
          g0 = acc[i][0][r] + xp[cidx[0]];
          g1 = acc[i][1][r] + xp[cidx[1]];
          g2 = acc[i][2][r] + xp[cidx[2]];
          g3 = acc[i][3][r] + xp[cidx[3]];
        } else {
          g0 = acc[i][0][r] + bj[0];
          g1 = acc[i][1][r] + bj[1];
          g2 = acc[i][2][r] + bj[2];
          g3 = acc[i][3][r] + bj[3];
        }
        float ig = sigf(g0), fg = sigf(g1), gg = tanh_(g2), og = sigf(g3);
        size_t si = (size_t)row*1024 + u;
        float cn = fg * cst[si] + ig * gg;
        cst[si] = cn;
        float hn = og * tanh_(cn);
        u16 hb = f2bf(hn);
        hout[si] = hb;
        if (MODE == 2) hout2[(size_t)row*32768 + u] = hb;  // feats[b][t][u]
      }
    }
  }
}

// ---------------------------------------------------------------------------
extern "C" void kernel_launch(void* const* d_in, const int* in_sizes, int n_in,
                              void* d_out, int out_size, void* d_ws, size_t ws_size,
                              hipStream_t stream)
{
  (void)in_sizes; (void)n_in; (void)out_size; (void)ws_size;
  const float* z    = (const float*)d_in[0];
  const float* gam  = (const float*)d_in[1];
  const float* bet  = (const float*)d_in[2];
  const float* Wih0 = (const float*)d_in[3];
  const float* Whh0 = (const float*)d_in[4];
  const float* bih0 = (const float*)d_in[5];
  const float* bhh0 = (const float*)d_in[6];
  const float* Wih1 = (const float*)d_in[7];
  const float* Whh1 = (const float*)d_in[8];
  const float* bih1 = (const float*)d_in[9];
  const float* bhh1 = (const float*)d_in[10];
  const float* Wlin = (const float*)d_in[11];
  const float* blin = (const float*)d_in[12];
  float* out = (float*)d_out;

  char* p = (char*)d_ws;
  auto alloc = [&](size_t b) -> void* { void* r = (void*)p; p += (b + 255) & ~(size_t)255; return r; };
  u16*  Wih0p = (u16*)alloc((size_t)4096*1024*2);
  u16*  Whh0p = (u16*)alloc((size_t)4096*1024*2);
  u16*  W1p   = (u16*)alloc((size_t)4096*2048*2);   // [W_ih1 | W_hh1] along K
  u16*  Wlinp = (u16*)alloc((size_t)1024*1024*2);
  float* Bx0  = (float*)alloc(4096*4);
  float* B1   = (float*)alloc(4096*4);
  float* X0p  = (float*)alloc((size_t)1024*4096*4);
  u16*  H0a   = (u16*)alloc((size_t)1024*1024*2);
  u16*  H0b   = (u16*)alloc((size_t)1024*1024*2);
  u16*  H1a   = (u16*)alloc((size_t)1024*1024*2);
  u16*  H1b   = (u16*)alloc((size_t)1024*1024*2);
  float* C0   = (float*)alloc((size_t)1024*1024*4);
  float* C1   = (float*)alloc((size_t)1024*1024*4);
  u16*  Feats = (u16*)alloc((size_t)1024*32*1024*2);
  float* PS   = (float*)alloc(16*1024*4);
  float* PQ   = (float*)alloc(16*1024*4);
  float* Sc   = (float*)alloc(1024*4);
  float* Sh   = (float*)alloc(1024*4);

  // prep
  bn_stats<<<64, 256, 0, stream>>>(z, PS, PQ);
  bn_fin<<<4, 256, 0, stream>>>(PS, PQ, gam, bet, Sc, Sh);
  bn_norm<<<64, 256, 0, stream>>>(z, Sc, Sh, H0a, H1a, C0, C1);
  conv_w<<<4096, 256, 0, stream>>>(Wih0, Wih0p, 1024, 0, 1);
  conv_w<<<4096, 256, 0, stream>>>(Whh0, Whh0p, 1024, 0, 1);
  conv_w<<<4096, 256, 0, stream>>>(Wih1, W1p, 2048, 0, 1);
  conv_w<<<4096, 256, 0, stream>>>(Whh1, W1p, 2048, 1024, 1);
  conv_w<<<1024, 256, 0, stream>>>(Wlin, Wlinp, 1024, 0, 0);
  bias_k<<<16, 256, 0, stream>>>(bih0, bhh0, bih1, bhh1, Bx0, B1);

  // x0_proj = zn @ W_ih0p^T + (b_ih0 + b_hh0)   (constant over steps)
  gemm_k<0><<<dim3(32,8), 256, 0, stream>>>(H0a, nullptr, 1024, Wih0p, 1024, Bx0,
                                            nullptr, nullptr, nullptr, X0p);

  u16* h0b[2] = {H0a, H0b};
  u16* h1b[2] = {H1a, H1b};
  for (int step = 0; step < 32; ++step){
    int cur = step & 1, nxt = cur ^ 1;
    gemm_k<1><<<dim3(32,8), 256, 0, stream>>>(h0b[cur], nullptr, 1024, Whh0p, 1024, X0p,
                                              C0, h0b[nxt], nullptr, nullptr);
    gemm_k<2><<<dim3(32,8), 256, 0, stream>>>(h0b[nxt], h1b[cur], 1024, W1p, 2048, B1,
                                              C1, h1b[nxt], Feats + (size_t)step*1024, nullptr);
  }

  // out = feats @ W_lin^T + b_lin
  gemm_k<3><<<dim3(8,256), 256, 0, stream>>>(Feats, nullptr, 1024, Wlinp, 1024, blin,
                                             nullptr, nullptr, nullptr, out);
}